// Round 2
// baseline (3573.418 us; speedup 1.0000x reference)
//
#include <hip/hip_runtime.h>
#include <cstdint>
#include <cstddef>

#define NNODES 100000
#define NEDGES 1600000
#define DIM 128
#define NREL 8
#define NSEG (NNODES * NREL)                       // 800,000 segments
#define SCAN_BLK 2048
#define NSCAN ((NSEG + SCAN_BLK - 1) / SCAN_BLK)   // 391 scan blocks

// ---------------------------------------------------------------- counts ----
__global__ __launch_bounds__(256) void count_kernel(const int* __restrict__ dst,
                                                    const int* __restrict__ et,
                                                    int* __restrict__ cnt) {
    int e = blockIdx.x * 256 + threadIdx.x;
    if (e < NEDGES) atomicAdd(&cnt[dst[e] * NREL + et[e]], 1);
}

// ------------------------------------------------------ 3-pass excl scan ----
__global__ __launch_bounds__(256) void scan_pass1(const int* __restrict__ cnt,
                                                  int* __restrict__ bsum) {
    int base = blockIdx.x * SCAN_BLK + threadIdx.x * 8;
    int s = 0;
#pragma unroll
    for (int j = 0; j < 8; ++j) {
        int i = base + j;
        if (i < NSEG) s += cnt[i];
    }
    __shared__ int ws[4];
    for (int d = 1; d < 64; d <<= 1) s += __shfl_xor(s, d);
    int lane = threadIdx.x & 63, w = threadIdx.x >> 6;
    if (lane == 0) ws[w] = s;
    __syncthreads();
    if (threadIdx.x == 0) bsum[blockIdx.x] = ws[0] + ws[1] + ws[2] + ws[3];
}

// single wave: exclusive scan of the 391 block sums, in place
__global__ __launch_bounds__(64) void scan_pass2(int* __restrict__ bsum) {
    int lane = threadIdx.x;
    int vals[7];
    int s = 0;
#pragma unroll
    for (int j = 0; j < 7; ++j) {
        int i = lane * 7 + j;
        vals[j] = (i < NSCAN) ? bsum[i] : 0;
        s += vals[j];
    }
    int incl = s;
    for (int d = 1; d < 64; d <<= 1) {
        int u = __shfl_up(incl, d);
        if (lane >= d) incl += u;
    }
    int base = incl - s;   // exclusive base of this lane's chunk
#pragma unroll
    for (int j = 0; j < 7; ++j) {
        int i = lane * 7 + j;
        if (i < NSCAN) bsum[i] = base;
        base += vals[j];
    }
}

__global__ __launch_bounds__(256) void scan_pass3(const int* __restrict__ cnt,
                                                  const int* __restrict__ bsum,
                                                  int* __restrict__ segend) {
    int tid = threadIdx.x;
    int base = blockIdx.x * SCAN_BLK + tid * 8;
    int v[8];
    int s = 0;
#pragma unroll
    for (int j = 0; j < 8; ++j) {
        int i = base + j;
        v[j] = (i < NSEG) ? cnt[i] : 0;
        s += v[j];
    }
    int lane = tid & 63, w = tid >> 6;
    int incl = s;
    for (int d = 1; d < 64; d <<= 1) {
        int u = __shfl_up(incl, d);
        if (lane >= d) incl += u;
    }
    __shared__ int wtot[4];
    if (lane == 63) wtot[w] = incl;
    __syncthreads();
    int wbase = 0;
#pragma unroll
    for (int k = 0; k < 4; ++k)
        if (k < w) wbase += wtot[k];
    int tbase = bsum[blockIdx.x] + wbase + (incl - s);
#pragma unroll
    for (int j = 0; j < 8; ++j) {
        int i = base + j;
        if (i < NSEG) segend[i] = tbase;   // exclusive offset; becomes seg END after bucketing
        tbase += v[j];
    }
}

// --------------------------------------------------------------- bucket ----
// After this kernel, segend[seg] == CSR offset of seg+1; begin(seg) is
// segend[seg-1] (0 for seg 0).
__global__ __launch_bounds__(256) void bucket_kernel(const int* __restrict__ src,
                                                     const int* __restrict__ dst,
                                                     const int* __restrict__ et,
                                                     int* __restrict__ segend,
                                                     int* __restrict__ ssrc) {
    int e = blockIdx.x * 256 + threadIdx.x;
    if (e >= NEDGES) return;
    int seg = dst[e] * NREL + et[e];
    int p = atomicAdd(&segend[seg], 1);
    ssrc[p] = src[e];
}

// ---------------------------------------------------------- fused layer ----
// Per node n: A = [ mean_r0 .. mean_r7 | feat_n ]  (1152 floats, in LDS),
// out[n,h] = relu(bias[h] + sum_k A[k] * W[k,h]) with W = [Wrel ; Wroot].
// Block = 256 threads = 8 nodes; 32-lane group per node.
#define AROW 1156   // 1152 padded +4: breaks the 1152 % 32 == 0 bank stride

#define FMA4(av, wv)                         \
    {                                        \
        acc.x = fmaf((av), (wv).x, acc.x);   \
        acc.y = fmaf((av), (wv).y, acc.y);   \
        acc.z = fmaf((av), (wv).z, acc.z);   \
        acc.w = fmaf((av), (wv).w, acc.w);   \
    }

__global__ __launch_bounds__(256) void fused_layer(
    const float* __restrict__ feat, const int* __restrict__ segend,
    const int* __restrict__ ssrc, const float* __restrict__ Wrel,
    const float* __restrict__ Wroot, const float* __restrict__ bias,
    float* __restrict__ out) {
    __shared__ float A[8][AROW];
    const int tid = threadIdx.x;
    const int g = tid >> 5, lane = tid & 31;
    const int n = blockIdx.x * 8 + g;

    // ---- on-the-fly segment means (8 relations) ----
    const int segbase = n * NREL;
    int beg = (segbase == 0) ? 0 : segend[segbase - 1];
    for (int r = 0; r < NREL; ++r) {
        const int end = segend[segbase + r];
        float4 acc = make_float4(0.f, 0.f, 0.f, 0.f);
        for (int e = beg; e < end; ++e) {
            const int s = ssrc[e];
            const float4 vv = *(const float4*)(feat + (size_t)s * DIM + lane * 4);
            acc.x += vv.x; acc.y += vv.y; acc.z += vv.z; acc.w += vv.w;
        }
        const int deg = end - beg;
        const float invc = 1.0f / (float)(deg > 1 ? deg : 1);
        acc.x *= invc; acc.y *= invc; acc.z *= invc; acc.w *= invc;
        *(float4*)(&A[g][r * DIM + lane * 4]) = acc;
        beg = end;
    }
    *(float4*)(&A[g][NREL * DIM + lane * 4]) =
        *(const float4*)(feat + (size_t)n * DIM + lane * 4);
    __syncthreads();

    // ---- GEMV: each thread computes 4 output h's for its node ----
    const int h4 = lane * 4;
    const float* As = &A[g][0];
    float4 acc = make_float4(0.f, 0.f, 0.f, 0.f);

#pragma unroll 2
    for (int k = 0; k < 1024; k += 4) {
        const float4 a = *(const float4*)(As + k);
        const float* wp = Wrel + (size_t)k * 128 + h4;
        const float4 w0 = *(const float4*)(wp);
        const float4 w1 = *(const float4*)(wp + 128);
        const float4 w2 = *(const float4*)(wp + 256);
        const float4 w3 = *(const float4*)(wp + 384);
        FMA4(a.x, w0);
        FMA4(a.y, w1);
        FMA4(a.z, w2);
        FMA4(a.w, w3);
    }
#pragma unroll 2
    for (int k = 0; k < 128; k += 4) {
        const float4 a = *(const float4*)(As + 1024 + k);
        const float* wp = Wroot + (size_t)k * 128 + h4;
        const float4 w0 = *(const float4*)(wp);
        const float4 w1 = *(const float4*)(wp + 128);
        const float4 w2 = *(const float4*)(wp + 256);
        const float4 w3 = *(const float4*)(wp + 384);
        FMA4(a.x, w0);
        FMA4(a.y, w1);
        FMA4(a.z, w2);
        FMA4(a.w, w3);
    }

    const float4 b = *(const float4*)(bias + h4);
    acc.x = fmaxf(acc.x + b.x, 0.f);
    acc.y = fmaxf(acc.y + b.y, 0.f);
    acc.z = fmaxf(acc.z + b.z, 0.f);
    acc.w = fmaxf(acc.w + b.w, 0.f);
    *(float4*)(out + (size_t)n * DIM + h4) = acc;
}

// ------------------------------------------------------------------ head ----
__global__ __launch_bounds__(256) void final_kernel(const float* __restrict__ h2,
                                                    const float* __restrict__ w,
                                                    const float* __restrict__ b,
                                                    float* __restrict__ out) {
    int gid = blockIdx.x * 256 + threadIdx.x;
    int node = gid >> 6;
    int lane = gid & 63;
    if (node >= NNODES) return;
    const float* row = h2 + (size_t)node * DIM;
    float v = row[lane] * w[lane] + row[lane + 64] * w[lane + 64];
#pragma unroll
    for (int off = 32; off; off >>= 1) v += __shfl_xor(v, off);
    if (lane == 0) out[node] = 1.0f / (1.0f + __expf(-(v + b[0])));
}

// ---------------------------------------------------------------- launch ----
extern "C" void kernel_launch(void* const* d_in, const int* in_sizes, int n_in,
                              void* d_out, int out_size, void* d_ws, size_t ws_size,
                              hipStream_t stream) {
    const float* x      = (const float*)d_in[0];
    const int*   ei     = (const int*)d_in[1];
    const int*   et     = (const int*)d_in[2];
    const float* Wrel1  = (const float*)d_in[3];
    const float* Wroot1 = (const float*)d_in[4];
    const float* b1     = (const float*)d_in[5];
    const float* Wrel2  = (const float*)d_in[6];
    const float* Wroot2 = (const float*)d_in[7];
    const float* b2     = (const float*)d_in[8];
    const float* outw   = (const float*)d_in[9];
    const float* outb   = (const float*)d_in[10];
    const int* src = ei;
    const int* dst = ei + NEDGES;

    // workspace layout (≈115 MB total)
    char* ws = (char*)d_ws;
    int*   cnt    = (int*)(ws + 0);            //  3,200,000 B
    int*   bsum   = (int*)(ws + 3200256);      //      4,096 B
    int*   segend = (int*)(ws + 3204352);      //  3,200,000 B
    int*   ssrc   = (int*)(ws + 6404608);      //  6,400,000 B
    float* h1     = (float*)(ws + 12804864);   // 51,200,000 B
    float* h2     = (float*)(ws + 64004864);   // 51,200,000 B
    // end: 115,204,864 B

    hipMemsetAsync(cnt, 0, (size_t)NSEG * 4, stream);
    count_kernel<<<(NEDGES + 255) / 256, 256, 0, stream>>>(dst, et, cnt);
    scan_pass1<<<NSCAN, 256, 0, stream>>>(cnt, bsum);
    scan_pass2<<<1, 64, 0, stream>>>(bsum);
    scan_pass3<<<NSCAN, 256, 0, stream>>>(cnt, bsum, segend);
    bucket_kernel<<<(NEDGES + 255) / 256, 256, 0, stream>>>(src, dst, et, segend, ssrc);

    fused_layer<<<NNODES / 8, 256, 0, stream>>>(x,  segend, ssrc, Wrel1, Wroot1, b1, h1);
    fused_layer<<<NNODES / 8, 256, 0, stream>>>(h1, segend, ssrc, Wrel2, Wroot2, b2, h2);

    final_kernel<<<(NNODES * 64 + 255) / 256, 256, 0, stream>>>(h2, outw, outb, (float*)d_out);
}

// Round 3
// 734.946 us; speedup vs baseline: 4.8621x; 4.8621x over previous
//
#include <hip/hip_runtime.h>
#include <cstdint>
#include <cstddef>

#define NNODES 100000
#define NEDGES 1600000
#define DIM 128
#define NREL 8
#define NSEG (NNODES * NREL)                       // 800,000 segments
#define SCAN_BLK 2048
#define NSCAN ((NSEG + SCAN_BLK - 1) / SCAN_BLK)   // 391 scan blocks
#define KTOT 1152                                  // 8*128 rel + 128 root
#define NKT (KTOT / 32)                            // 36 K-steps
#define AROW 1160                                  // 1152 + 8 bf16 pad (16B) -> bank stride 2320B

typedef float f32x4 __attribute__((ext_vector_type(4)));
typedef short short8 __attribute__((ext_vector_type(8)));

__device__ inline float bf2f(unsigned short u) {
    return __uint_as_float(((unsigned)u) << 16);
}
__device__ inline unsigned short f2bf(float f) {   // RNE, finite inputs
    unsigned u = __float_as_uint(f);
    return (unsigned short)((u + 0x7fffu + ((u >> 16) & 1u)) >> 16);
}

// ---------------------------------------------------------------- counts ----
__global__ __launch_bounds__(256) void count_kernel(const int* __restrict__ dst,
                                                    const int* __restrict__ et,
                                                    int* __restrict__ cnt) {
    int e = blockIdx.x * 256 + threadIdx.x;
    if (e < NEDGES) atomicAdd(&cnt[dst[e] * NREL + et[e]], 1);
}

// ------------------------------------------------------ 3-pass excl scan ----
__global__ __launch_bounds__(256) void scan_pass1(const int* __restrict__ cnt,
                                                  int* __restrict__ bsum) {
    int base = blockIdx.x * SCAN_BLK + threadIdx.x * 8;
    int s = 0;
#pragma unroll
    for (int j = 0; j < 8; ++j) {
        int i = base + j;
        if (i < NSEG) s += cnt[i];
    }
    __shared__ int ws[4];
    for (int d = 1; d < 64; d <<= 1) s += __shfl_xor(s, d);
    int lane = threadIdx.x & 63, w = threadIdx.x >> 6;
    if (lane == 0) ws[w] = s;
    __syncthreads();
    if (threadIdx.x == 0) bsum[blockIdx.x] = ws[0] + ws[1] + ws[2] + ws[3];
}

__global__ __launch_bounds__(64) void scan_pass2(int* __restrict__ bsum) {
    int lane = threadIdx.x;
    int vals[7];
    int s = 0;
#pragma unroll
    for (int j = 0; j < 7; ++j) {
        int i = lane * 7 + j;
        vals[j] = (i < NSCAN) ? bsum[i] : 0;
        s += vals[j];
    }
    int incl = s;
    for (int d = 1; d < 64; d <<= 1) {
        int u = __shfl_up(incl, d);
        if (lane >= d) incl += u;
    }
    int base = incl - s;
#pragma unroll
    for (int j = 0; j < 7; ++j) {
        int i = lane * 7 + j;
        if (i < NSCAN) bsum[i] = base;
        base += vals[j];
    }
}

__global__ __launch_bounds__(256) void scan_pass3(const int* __restrict__ cnt,
                                                  const int* __restrict__ bsum,
                                                  int* __restrict__ segend) {
    int tid = threadIdx.x;
    int base = blockIdx.x * SCAN_BLK + tid * 8;
    int v[8];
    int s = 0;
#pragma unroll
    for (int j = 0; j < 8; ++j) {
        int i = base + j;
        v[j] = (i < NSEG) ? cnt[i] : 0;
        s += v[j];
    }
    int lane = tid & 63, w = tid >> 6;
    int incl = s;
    for (int d = 1; d < 64; d <<= 1) {
        int u = __shfl_up(incl, d);
        if (lane >= d) incl += u;
    }
    __shared__ int wtot[4];
    if (lane == 63) wtot[w] = incl;
    __syncthreads();
    int wbase = 0;
#pragma unroll
    for (int k = 0; k < 4; ++k)
        if (k < w) wbase += wtot[k];
    int tbase = bsum[blockIdx.x] + wbase + (incl - s);
#pragma unroll
    for (int j = 0; j < 8; ++j) {
        int i = base + j;
        if (i < NSEG) segend[i] = tbase;   // becomes segment END after bucketing
        tbase += v[j];
    }
}

// --------------------------------------------------------------- bucket ----
__global__ __launch_bounds__(256) void bucket_kernel(const int* __restrict__ src,
                                                     const int* __restrict__ dst,
                                                     const int* __restrict__ et,
                                                     int* __restrict__ segend,
                                                     int* __restrict__ ssrc) {
    int e = blockIdx.x * 256 + threadIdx.x;
    if (e >= NEDGES) return;
    int seg = dst[e] * NREL + et[e];
    int p = atomicAdd(&segend[seg], 1);
    ssrc[p] = src[e];
}

// --------------------------------------------------------------- fp32->bf16 -
__global__ __launch_bounds__(256) void cvt_bf16(const float* __restrict__ in,
                                                unsigned short* __restrict__ outp,
                                                int nelem4) {
    int i = blockIdx.x * 256 + threadIdx.x;
    if (i >= nelem4) return;
    float4 v = *(const float4*)(in + (size_t)i * 4);
    ushort4 o = make_ushort4(f2bf(v.x), f2bf(v.y), f2bf(v.z), f2bf(v.w));
    *(ushort4*)(outp + (size_t)i * 4) = o;
}

// ----------------------------------------------------- pack W into B-frags --
// B-frag layout (16x16x32 bf16): lane holds B[k=(lane>>4)*8+j][n=lane&15].
// Packed: Wp[(kt*8 + ht)*64 + lane][8] bf16 -> one coalesced 16B load per lane.
__global__ __launch_bounds__(64) void pack_w(const float* __restrict__ Wrel,
                                             const float* __restrict__ Wroot,
                                             unsigned short* __restrict__ Wp) {
    const int kt = blockIdx.x >> 3, ht = blockIdx.x & 7;
    const int lane = threadIdx.x;
    const int col = ht * 16 + (lane & 15);
    const int kbase = kt * 32 + (lane >> 4) * 8;
    unsigned short vals[8];
#pragma unroll
    for (int j = 0; j < 8; ++j) {
        int k = kbase + j;
        float f = (k < 1024) ? Wrel[(size_t)k * 128 + col]
                             : Wroot[(size_t)(k - 1024) * 128 + col];
        vals[j] = f2bf(f);
    }
    unsigned short* dst = Wp + ((size_t)blockIdx.x * 64 + lane) * 8;
#pragma unroll
    for (int j = 0; j < 8; ++j) dst[j] = vals[j];
}

// ---------------------------------------------------------- fused layer ----
// Phase 1: 16 lanes/node build A = [mean_r0..mean_r7 | feat_n] (bf16) in LDS.
// Phase 2: 4 waves x 2 h-tiles, 36 K-steps of mfma_f32_16x16x32_bf16.
__global__ __launch_bounds__(256) void fused_layer(
    const unsigned short* __restrict__ feat,   // bf16 [N][128]
    const int* __restrict__ segend,
    const int* __restrict__ ssrc,
    const unsigned short* __restrict__ Wp,     // packed B-frags
    const float* __restrict__ bias,
    unsigned short* __restrict__ out) {        // bf16 [N][128], relu'd
    __shared__ unsigned short A[16][AROW];
    const int tid = threadIdx.x;

    // ---- phase 1: aggregation ----
    {
        const int g = tid >> 4, l16 = tid & 15;
        const int n = blockIdx.x * 16 + g;
        const int segbase = n * NREL;
        int beg = (segbase == 0) ? 0 : segend[segbase - 1];
        for (int r = 0; r < NREL; ++r) {
            const int end = segend[segbase + r];
            float acc[8] = {0.f, 0.f, 0.f, 0.f, 0.f, 0.f, 0.f, 0.f};
            for (int e = beg; e < end; ++e) {
                const int s = ssrc[e];
                const short8 v = *(const short8*)(feat + (size_t)s * DIM + l16 * 8);
#pragma unroll
                for (int j = 0; j < 8; ++j) acc[j] += bf2f((unsigned short)v[j]);
            }
            const int deg = end - beg;
            const float invc = 1.0f / (float)(deg > 1 ? deg : 1);
            unsigned short* ap = &A[g][r * DIM + l16 * 8];
#pragma unroll
            for (int j = 0; j < 8; ++j) ap[j] = f2bf(acc[j] * invc);
            beg = end;
        }
        // root feature (already bf16) -> A[.., 1024..1151]
        *(short8*)(&A[g][NREL * DIM + l16 * 8]) =
            *(const short8*)(feat + (size_t)n * DIM + l16 * 8);
    }
    __syncthreads();

    // ---- phase 2: MFMA GEMM ----
    const int lane = tid & 63;
    const int w = tid >> 6;            // wave id: h-tiles 2w, 2w+1
    const int m = lane & 15, kq = lane >> 4;
    const unsigned short* arow = &A[m][kq * 8];
    f32x4 acc0 = {0.f, 0.f, 0.f, 0.f};
    f32x4 acc1 = {0.f, 0.f, 0.f, 0.f};

#pragma unroll 4
    for (int kt = 0; kt < NKT; ++kt) {
        short8 a = *(const short8*)(arow + kt * 32);
        short8 b0 = *(const short8*)(Wp + ((size_t)(kt * 8 + 2 * w) * 64 + lane) * 8);
        short8 b1 = *(const short8*)(Wp + ((size_t)(kt * 8 + 2 * w + 1) * 64 + lane) * 8);
        acc0 = __builtin_amdgcn_mfma_f32_16x16x32_bf16(a, b0, acc0, 0, 0, 0);
        acc1 = __builtin_amdgcn_mfma_f32_16x16x32_bf16(a, b1, acc1, 0, 0, 0);
    }

    // ---- epilogue: bias + relu + bf16 store ----
    // C/D: col = lane&15, row = (lane>>4)*4 + reg
    const int col = lane & 15;
    const int rbase = (lane >> 4) * 4;
    const int h0 = 2 * w * 16 + col;
    const int h1 = h0 + 16;
    const float bv0 = bias[h0], bv1 = bias[h1];
#pragma unroll
    for (int r = 0; r < 4; ++r) {
        const size_t nrow = (size_t)(blockIdx.x * 16 + rbase + r) * DIM;
        out[nrow + h0] = f2bf(fmaxf(acc0[r] + bv0, 0.f));
        out[nrow + h1] = f2bf(fmaxf(acc1[r] + bv1, 0.f));
    }
}

// ------------------------------------------------------------------ head ----
__global__ __launch_bounds__(256) void final_kernel(const unsigned short* __restrict__ h2,
                                                    const float* __restrict__ w,
                                                    const float* __restrict__ b,
                                                    float* __restrict__ out) {
    int gid = blockIdx.x * 256 + threadIdx.x;
    int node = gid >> 6;
    int lane = gid & 63;
    if (node >= NNODES) return;
    const unsigned short* row = h2 + (size_t)node * DIM;
    float v = bf2f(row[lane]) * w[lane] + bf2f(row[lane + 64]) * w[lane + 64];
#pragma unroll
    for (int off = 32; off; off >>= 1) v += __shfl_xor(v, off);
    if (lane == 0) out[node] = 1.0f / (1.0f + __expf(-(v + b[0])));
}

// ---------------------------------------------------------------- launch ----
extern "C" void kernel_launch(void* const* d_in, const int* in_sizes, int n_in,
                              void* d_out, int out_size, void* d_ws, size_t ws_size,
                              hipStream_t stream) {
    const float* x      = (const float*)d_in[0];
    const int*   ei     = (const int*)d_in[1];
    const int*   et     = (const int*)d_in[2];
    const float* Wrel1  = (const float*)d_in[3];
    const float* Wroot1 = (const float*)d_in[4];
    const float* b1     = (const float*)d_in[5];
    const float* Wrel2  = (const float*)d_in[6];
    const float* Wroot2 = (const float*)d_in[7];
    const float* b2     = (const float*)d_in[8];
    const float* outw   = (const float*)d_in[9];
    const float* outb   = (const float*)d_in[10];
    const int* src = ei;
    const int* dst = ei + NEDGES;

    // workspace layout (~90 MB, all offsets 16B-aligned)
    char* ws = (char*)d_ws;
    int*            cnt    = (int*)(ws + 0);                     //  3,200,000
    int*            bsum   = (int*)(ws + 3200000);               //      4,096
    int*            segend = (int*)(ws + 3204096);               //  3,200,000
    int*            ssrc   = (int*)(ws + 6404096);               //  6,400,000
    unsigned short* xb     = (unsigned short*)(ws + 12804096);   // 25,600,000
    unsigned short* h1b    = (unsigned short*)(ws + 38404096);   // 25,600,000
    unsigned short* h2b    = (unsigned short*)(ws + 64004096);   // 25,600,000
    unsigned short* Wp1    = (unsigned short*)(ws + 89604096);   //    294,912
    unsigned short* Wp2    = (unsigned short*)(ws + 89899008);   //    294,912
    // end: 90,193,920 B

    hipMemsetAsync(cnt, 0, (size_t)NSEG * 4, stream);
    count_kernel<<<(NEDGES + 255) / 256, 256, 0, stream>>>(dst, et, cnt);
    scan_pass1<<<NSCAN, 256, 0, stream>>>(cnt, bsum);
    scan_pass2<<<1, 64, 0, stream>>>(bsum);
    scan_pass3<<<NSCAN, 256, 0, stream>>>(cnt, bsum, segend);
    bucket_kernel<<<(NEDGES + 255) / 256, 256, 0, stream>>>(src, dst, et, segend, ssrc);

    cvt_bf16<<<(NNODES * DIM / 4 + 255) / 256, 256, 0, stream>>>(x, xb, NNODES * DIM / 4);
    pack_w<<<NKT * 8, 64, 0, stream>>>(Wrel1, Wroot1, Wp1);
    pack_w<<<NKT * 8, 64, 0, stream>>>(Wrel2, Wroot2, Wp2);

    fused_layer<<<NNODES / 16, 256, 0, stream>>>(xb,  segend, ssrc, Wp1, b1, h1b);
    fused_layer<<<NNODES / 16, 256, 0, stream>>>(h1b, segend, ssrc, Wp2, b2, h2b);

    final_kernel<<<(NNODES * 64 + 255) / 256, 256, 0, stream>>>(h2b, outw, outb, (float*)d_out);
}